// Round 6
// baseline (392.691 us; speedup 1.0000x reference)
//
#include <hip/hip_runtime.h>
#include <math.h>

// Problem constants (from reference)
#define BB 8
#define SS 4096
#define DD 512
#define HH 512
#define MM (BB*SS)          // 32768 rows

// Scan chunking
constexpr int TCH = 64;              // timesteps per chunk
constexpr int NC  = SS / TCH;        // 64 chunks
constexpr int BH  = BB * HH;         // 4096 channels

// Flat GEMM tiling: block = 128x128, 4 waves, wave tile 64x64 (per matrix)
constexpr int BM = 128;
constexpr int BN = 128;

typedef short  short8  __attribute__((ext_vector_type(8)));
typedef float  float4v __attribute__((ext_vector_type(4)));

__device__ inline unsigned short f2bf(float f) {
    union { float f; unsigned u; } v; v.f = f;
    unsigned r = v.u + 0x7FFF + ((v.u >> 16) & 1);   // RNE
    return (unsigned short)(r >> 16);
}
__device__ inline float bf_lo(unsigned u) {          // low 16 bits -> float
    union { unsigned u; float f; } x; x.u = u << 16; return x.f;
}
__device__ inline float bf_hi(unsigned u) {          // high 16 bits -> float
    union { unsigned u; float f; } x; x.u = u & 0xffff0000u; return x.f;
}
__device__ inline float fast_rcp(float x) {          // v_rcp_f32, ~1ulp(22b)
    return __builtin_amdgcn_rcpf(x);
}

// ---------------------------------------------------------------------------
// fp32 -> bf16 conversion for X (8192 blocks) and the 4 weights (4x128 blocks)
// ---------------------------------------------------------------------------
__global__ __launch_bounds__(256)
void conv_all(const float* __restrict__ x,
              const float* __restrict__ w0, const float* __restrict__ w1,
              const float* __restrict__ w2, const float* __restrict__ w3,
              short* __restrict__ Xbf, short* __restrict__ Wbf)
{
    constexpr int XBLK = MM * DD / 8 / 256;   // 8192
    constexpr int WBLK = HH * DD / 8 / 256;   // 128
    const int bid = blockIdx.x;
    const float* src; short* dst; size_t base;
    if (bid < XBLK) {
        src = x; dst = Xbf;
        base = ((size_t)bid * 256 + threadIdx.x) * 8;
    } else {
        const int idx  = bid - XBLK;
        const int wsel = idx / WBLK;
        src = (wsel == 0) ? w0 : (wsel == 1) ? w1 : (wsel == 2) ? w2 : w3;
        dst = Wbf + (size_t)wsel * HH * DD;
        base = ((size_t)(idx % WBLK) * 256 + threadIdx.x) * 8;
    }
    float4 a = *(const float4*)(src + base);
    float4 b = *(const float4*)(src + base + 4);
    short8 r;
    r[0] = f2bf(a.x); r[1] = f2bf(a.y); r[2] = f2bf(a.z); r[3] = f2bf(a.w);
    r[4] = f2bf(b.x); r[5] = f2bf(b.y); r[6] = f2bf(b.z); r[7] = f2bf(b.w);
    *(short8*)(dst + base) = r;
}

// ---------------------------------------------------------------------------
// Barrier-free "flat" MFMA gate GEMM + fused in-register chunk-summary scan.
// No LDS: A and B fragments are loaded straight from global with the exact
// MFMA 16x16x32 operand layout (row = lane&15, k-slice = (lane>>4)*8).
// Weights (1 MB) are L1/L2-resident; X streams via LLC. The K-loop is a pure
// load<->MFMA interleave the compiler pipelines with fine-grained vmcnt.
//   kz = X·Wz + bz, kh = X·Wh + bh
//   a = sigmoid(-kz); v = (1-a)*g(kh); AV[m,n] = pack_bf16(v, a)
// Chunk summaries: each wave covers exactly one 64-timestep chunk (rows
// wm*64..+64) -> ordered compose in-lane (reg), cross-quad (__shfl_xor 16/32),
// then in-lane across mi. No LDS, no extra pass.
// ---------------------------------------------------------------------------
__global__ __launch_bounds__(256, 2)
void gemm_gate_mfma(const short* __restrict__ Xg, const short* __restrict__ Wz,
                    const float* __restrict__ bz, const short* __restrict__ Wh,
                    const float* __restrict__ bh, unsigned* __restrict__ AV,
                    float2* __restrict__ cAV)
{
    const int t    = threadIdx.x;
    const int wave = t >> 6;
    const int lane = t & 63;
    const int col16 = lane & 15;
    const int quad  = lane >> 4;
    const int wm = wave >> 1;          // 0/1: 64-row half (= chunk within block)
    const int wn = wave & 1;           // 0/1: 64-col half
    const int m0 = blockIdx.x * BM;
    const int n0 = blockIdx.y * BN;

    // Fragment base pointers (k-offset applied as immediate in the loop)
    const short* ap[4]; const short* zp[4]; const short* hp[4];
    #pragma unroll
    for (int mi = 0; mi < 4; ++mi)
        ap[mi] = Xg + (size_t)(m0 + wm*64 + mi*16 + col16) * DD + quad*8;
    #pragma unroll
    for (int nj = 0; nj < 4; ++nj) {
        zp[nj] = Wz + (size_t)(n0 + wn*64 + nj*16 + col16) * DD + quad*8;
        hp[nj] = Wh + (size_t)(n0 + wn*64 + nj*16 + col16) * DD + quad*8;
    }

    float4v accz[4][4], acch[4][4];
    #pragma unroll
    for (int i = 0; i < 4; ++i)
        #pragma unroll
        for (int j = 0; j < 4; ++j) {
            accz[i][j] = (float4v){0.f, 0.f, 0.f, 0.f};
            acch[i][j] = (float4v){0.f, 0.f, 0.f, 0.f};
        }

    // ---- K-loop: 16 steps of K=32; 12 loads + 32 MFMAs each; no barriers ----
    #pragma unroll
    for (int k = 0; k < DD; k += 32) {
        short8 af[4], bzf[4], bhf[4];
        #pragma unroll
        for (int mi = 0; mi < 4; ++mi) af[mi] = *(const short8*)(ap[mi] + k);
        #pragma unroll
        for (int nj = 0; nj < 4; ++nj) {
            bzf[nj] = *(const short8*)(zp[nj] + k);
            bhf[nj] = *(const short8*)(hp[nj] + k);
        }
        #pragma unroll
        for (int mi = 0; mi < 4; ++mi)
            #pragma unroll
            for (int nj = 0; nj < 4; ++nj) {
                accz[mi][nj] = __builtin_amdgcn_mfma_f32_16x16x32_bf16(af[mi], bzf[nj], accz[mi][nj], 0, 0, 0);
                acch[mi][nj] = __builtin_amdgcn_mfma_f32_16x16x32_bf16(af[mi], bhf[nj], acch[mi][nj], 0, 0, 0);
            }
    }

    // ---- epilogue: gates, AV stores, and in-register chunk summary ----
    // C/D layout: col=lane&15, row=quad*4+reg (m89/m91-verified).
    const int b  = m0 >> 12;                       // batch
    const int cg = ((m0 & 4095) >> 6) + wm;        // global chunk idx in batch

    #pragma unroll
    for (int nj = 0; nj < 4; ++nj) {
        const int n = n0 + wn*64 + nj*16 + col16;
        const float bzn = bz[n], bhn = bh[n];
        float TA[4], TV[4];                        // per-mi 16-row transfers
        #pragma unroll
        for (int mi = 0; mi < 4; ++mi) {
            const int rowb = m0 + wm*64 + mi*16 + quad*4;
            float cA_ = 1.0f, cV_ = 0.0f;
            #pragma unroll
            for (int reg = 0; reg < 4; ++reg) {
                const float kz = accz[mi][nj][reg] + bzn;
                const float kh = acch[mi][nj][reg] + bhn;
                const float a  = fast_rcp(1.0f + __expf(kz));   // sigmoid(-kz)
                const float sn = fast_rcp(1.0f + __expf(-kh));  // sigmoid(kh)
                const float ht = (kh >= 0.0f) ? (kh + 0.5f) : sn;
                const float v  = (1.0f - a) * ht;               // z * h_tilde
                const unsigned pav = ((unsigned)f2bf(v) << 16) | f2bf(a);
                AV[(size_t)(rowb + reg) * HH + n] = pav;
                // compose with the *rounded* values (consistent with replay)
                const float ar = bf_lo(pav), vr = bf_hi(pav);
                cV_ = fmaf(ar, cV_, vr);
                cA_ *= ar;
            }
            TA[mi] = cA_; TV[mi] = cV_;
        }
        // cross-quad ordered compose (rows quad*4+reg within each 16-block)
        #pragma unroll
        for (int mi = 0; mi < 4; ++mi) {
            {   // pair quads differing in bit0 (xor 16)
                const float As = TA[mi], Vs = TV[mi];
                const float Ap = __shfl_xor(As, 16), Vp = __shfl_xor(Vs, 16);
                TA[mi] = As * Ap;
                TV[mi] = (quad & 1) ? fmaf(As, Vp, Vs) : fmaf(Ap, Vs, Vp);
            }
            {   // pair quad-pairs differing in bit1 (xor 32)
                const float As = TA[mi], Vs = TV[mi];
                const float Ap = __shfl_xor(As, 32), Vp = __shfl_xor(Vs, 32);
                TA[mi] = As * Ap;
                TV[mi] = (quad & 2) ? fmaf(As, Vp, Vs) : fmaf(Ap, Vs, Vp);
            }
        }
        // chain the four 16-row transfers in row order
        float CA = TA[0], CV = TV[0];
        #pragma unroll
        for (int mi = 1; mi < 4; ++mi) {
            CV = fmaf(TA[mi], CV, TV[mi]);
            CA *= TA[mi];
        }
        if (quad == 0)
            cAV[(size_t)cg * BH + b * HH + n] = make_float2(CA, CV);
    }
}

// ---------------------------------------------------------------------------
// Scan apply (fp32 out, final layer): each (b,c) block computes its own carry
// prefix from the chunk summaries, then replays its chunk. Last-chunk blocks
// emit finals (= h at t = S-1).
// ---------------------------------------------------------------------------
__global__ __launch_bounds__(256)
void scan_apply_f32(const unsigned* __restrict__ AV,
                    const float2* __restrict__ cAV,
                    float* __restrict__ out, float* __restrict__ finals)
{
    const int h = blockIdx.x * 256 + threadIdx.x;
    const int b = blockIdx.y;
    const int c = blockIdx.z;
    const int ch = b * HH + h;
    float hcur = 0.5f;                  // h0 = g(0) = 0.5
    for (int cp = 0; cp < c; ++cp) {
        const float2 s = cAV[(size_t)cp * BH + ch];
        hcur = fmaf(s.x, hcur, s.y);
    }
    size_t base = ((size_t)(b * SS + c * TCH)) * HH + h;
    #pragma unroll 8
    for (int tt = 0; tt < TCH; ++tt) {
        const unsigned u = AV[base];
        hcur = fmaf(bf_lo(u), hcur, bf_hi(u));
        out[base] = hcur;
        base += HH;
    }
    if (c == NC - 1) finals[ch] = hcur;
}

// ---------------------------------------------------------------------------
// Scan apply (bf16 out): layer-0 hidden seq feeds only layer-1's GEMM.
// ---------------------------------------------------------------------------
__global__ __launch_bounds__(256)
void scan_apply_bf16(const unsigned* __restrict__ AV,
                     const float2* __restrict__ cAV,
                     short* __restrict__ out, float* __restrict__ finals)
{
    const int h = blockIdx.x * 256 + threadIdx.x;
    const int b = blockIdx.y;
    const int c = blockIdx.z;
    const int ch = b * HH + h;
    float hcur = 0.5f;
    for (int cp = 0; cp < c; ++cp) {
        const float2 s = cAV[(size_t)cp * BH + ch];
        hcur = fmaf(s.x, hcur, s.y);
    }
    size_t base = ((size_t)(b * SS + c * TCH)) * HH + h;
    #pragma unroll 8
    for (int tt = 0; tt < TCH; ++tt) {
        const unsigned u = AV[base];
        hcur = fmaf(bf_lo(u), hcur, bf_hi(u));
        out[base] = (short)f2bf(hcur);
        base += HH;
    }
    if (c == NC - 1) finals[ch] = hcur;
}

// ---------------------------------------------------------------------------
// Orchestration.  ws: AV(64MB) Xbf(32MB) Wbf(2MB) cAV(2MB) ~ 100MB
// ---------------------------------------------------------------------------
extern "C" void kernel_launch(void* const* d_in, const int* in_sizes, int n_in,
                              void* d_out, int out_size, void* d_ws, size_t ws_size,
                              hipStream_t stream)
{
    const float* x   = (const float*)d_in[0];
    const float* wz0 = (const float*)d_in[1];
    const float* bz0 = (const float*)d_in[2];
    const float* wh0 = (const float*)d_in[3];
    const float* bh0 = (const float*)d_in[4];
    const float* wz1 = (const float*)d_in[5];
    const float* bz1 = (const float*)d_in[6];
    const float* wh1 = (const float*)d_in[7];
    const float* bh1 = (const float*)d_in[8];

    float* out    = (float*)d_out;                // (B,S,H) layer-2 hidden seq
    float* finals = out + (size_t)MM * HH;        // (L,B,1,H)

    unsigned* AV  = (unsigned*)d_ws;                      // M*H packed bf16 (v|a)
    short* Xbf    = (short*)(AV + (size_t)MM * HH);       // M*D bf16
    short* Wbf    = Xbf + (size_t)MM * DD;                // 4 * H*D bf16
    float2* cAV   = (float2*)(Wbf + (size_t)4 * HH * DD); // NC*BH float2

    short* Wz0 = Wbf;
    short* Wh0 = Wbf + (size_t)1 * HH * DD;
    short* Wz1 = Wbf + (size_t)2 * HH * DD;
    short* Wh1 = Wbf + (size_t)3 * HH * DD;

    const dim3 gg(MM / BM, HH / BN);       // 256 x 4
    const dim3 gs(HH / 256, BB, NC);       // 2 x 8 x 64

    // ---- conversions (one launch: X + all 4 weights) ----
    conv_all<<<MM * DD / 8 / 256 + 4 * (HH * DD / 8 / 256), 256, 0, stream>>>(
        x, wz0, wh0, wz1, wh1, Xbf, Wbf);

    // ---- layer 0 ----
    gemm_gate_mfma <<<gg, 256, 0, stream>>>(Xbf, Wz0, bz0, Wh0, bh0, AV, cAV);
    scan_apply_bf16<<<gs, 256, 0, stream>>>(AV, cAV, Xbf, finals);            // finals[0]

    // ---- layer 1 ----
    gemm_gate_mfma <<<gg, 256, 0, stream>>>(Xbf, Wz1, bz1, Wh1, bh1, AV, cAV);
    scan_apply_f32 <<<gs, 256, 0, stream>>>(AV, cAV, out, finals + BH);       // finals[1]
}